// Round 1
// 126.837 us; speedup vs baseline: 1.0592x; 1.0592x over previous
//
#include <hip/hip_runtime.h>
#include <math.h>

// Problem constants (fixed by the reference setup_inputs)
#define BB 4
#define TT 4096
#define SS 4096
#define EE 512
#define HH 64
#define NN 128          // Chebyshev nodes / polynomial degree
#define XR 6.0f         // interpolation half-range for x

// Workspace layout (floats), NO aliasing (~410 KB):
//  O      : [B][N][H]   ws + 0      (32768)  atomic fp32 accumulator (zeroed by prep)
//  Cmat   : [N][N]      ws + 32768  (16384)
//  qnA    : bf16 A-frags +49152     (4096 float-slots = 8192 bf16)
//  Wfrag  : bf16 B-frags +53248     (32768 float-slots = 65536 bf16)
//  Sm_part: [B][32][N]  +86016      (16384)
//
// Session lessons (measured):
//  R9 : cooperative grid.sync() ~50 us each on MI355X (8 non-coherent XCD
//       L2s -> device-scope spin). Graph dispatch boundaries are ~5 us.
//  R10: kvattn grid = 256 blocks on 256 CUs -> occupancy is GRID-limited at
//       1 block/CU; LDS reduction (69->36 KB) buys nothing and the extra
//       barriers + duplicate Wfrag pass cost +2.7 us. Keep 64 KB staging.
//  R11 (this round): fold oy into kvattn via global atomicAdd on O (128 KB,
//       unique (j,h) per lane within a block, 64-way cross-block over time);
//       Sm via Chebyshev recurrence T_m(x) instead of cosf(m*acos x) — no
//       trig; tanh via v_exp+v_rcp (outputs are bf16-rounded, 1e-6 tanh is
//       free). ynode moved to final's head (32 KB L2 + 32 tanh/thread).

typedef __attribute__((ext_vector_type(8))) __bf16 bf16x8;
typedef __attribute__((ext_vector_type(16))) float f32x16;

__device__ __forceinline__ unsigned short f2b(float f) {
  unsigned int u = __float_as_uint(f);
  return (unsigned short)((u + 0x7FFFu + ((u >> 16) & 1u)) >> 16);  // RNE
}

// tanh via HW exp+rcp: rel err ~1e-6, ~5 VALU ops vs ~25 for ocml tanhf.
// Negative side underflows gracefully (e->0 => -1); clamp avoids inf*0 NaN.
__device__ __forceinline__ float fast_tanh(float v) {
  float e = __expf(fminf(60.0f, 2.0f * v));
  return (e - 1.0f) * __builtin_amdgcn_rcpf(e + 1.0f);
}

// ---------------------------------------------------------------------------
// Kernel A (prep+sm fused):
//   blocks [0,64)    : Wfrag pack (kw||vw fp32 -> MFMA B-frag bf16)
//   blocks [64,128)  : Cmat[m][j] = cos(m*pi*(j+.5)/N); also zero O (128 KB)
//   blocks [128,160) : qnA bf16 A-frags of qn[j][h] = tanh(x_j*qw[h]+qb[h])
//   blocks [160,288) : Sm_part[b][chunk][m] = sum_{128 t} T_m(xhat_t)
//                      via 1-FMA Chebyshev recurrence + LDS transpose-sum
// ---------------------------------------------------------------------------
__global__ __launch_bounds__(256) void prep_sm_kernel(
    const float* __restrict__ kw, const float* __restrict__ vw,
    const float* __restrict__ qw, const float* __restrict__ qb,
    const float* __restrict__ x, unsigned int* __restrict__ Wfrag,
    float* __restrict__ Cmat, unsigned short* __restrict__ qnA,
    float* __restrict__ Sm_part, float* __restrict__ Oz) {
  const int blk = blockIdx.x;
  if (blk < 64) {
    // Wfrag pack: ((nblk*32 + kstep)*64 + lane)*8 + j  (bf16 units)
    int idx = blk * 256 + threadIdx.x;  // [0, 16384)
    int jq = idx & 1;
    int l = (idx >> 1) & 63;
    int ks = (idx >> 7) & 31;
    int nb = idx >> 12;
    int n = nb * 32 + (l & 31);
    int k = ks * 16 + (l >> 5) * 8 + jq * 4;
    const float* row = (n < HH) ? (kw + n * EE + k) : (vw + (n - HH) * EE + k);
    float4 wv = *(const float4*)row;
    Wfrag[idx * 2] = (unsigned int)f2b(wv.x) | ((unsigned int)f2b(wv.y) << 16);
    Wfrag[idx * 2 + 1] =
        (unsigned int)f2b(wv.z) | ((unsigned int)f2b(wv.w) << 16);
  } else if (blk < 128) {
    int idx = (blk - 64) * 256 + threadIdx.x;  // [0, N*N)
    int m = idx >> 7;
    int j = idx & (NN - 1);
    Cmat[idx] = (float)cos((double)m * (M_PI * (j + 0.5) / NN));
    // zero the atomic O accumulator: 8192 float4 = 128 KB
    if (idx < 8192) ((float4*)Oz)[idx] = make_float4(0.f, 0.f, 0.f, 0.f);
  } else if (blk < 160) {
    int idx = (blk - 128) * 256 + threadIdx.x;  // [0, 8192)
    int h = idx & 63;
    int j = idx >> 6;
    double th = M_PI * (j + 0.5) / NN;
    float xj = (float)(XR * cos(th));
    float val = tanhf(fmaf(xj, qw[h], qb[h]));
    // A-frag position for element (m=j, k=h):
    int pos = (((j >> 5) * 4 + (h >> 4)) * 64 + (j & 31) + 32 * ((h >> 3) & 1)) * 8 +
              (h & 7);
    qnA[pos] = f2b(val);
  } else {
    // Sm via Chebyshev recurrence: cos(m*acos(xhat)) == T_m(xhat), exactly.
    // Tm[i][m], padded to 129 -> both row-write and column-read conflict-free.
    __shared__ float Tm[128][NN + 1];  // 66048 B (2 blocks/CU still fits)
    int blk2 = blk - 160;  // [0,128)
    int b = blk2 >> 5;
    int chunk = blk2 & 31;
    int tid = threadIdx.x;
    if (tid < 128) {
      float xh = x[b * TT + chunk * 128 + tid] * (1.0f / XR);
      xh = fminf(1.0f, fmaxf(-1.0f, xh));
      Tm[tid][0] = 1.0f;
      Tm[tid][1] = xh;
      float x2 = 2.0f * xh;
      float tm2 = 1.0f, tm1 = xh;
#pragma unroll 6
      for (int m = 2; m < NN; ++m) {
        float t = fmaf(x2, tm1, -tm2);
        Tm[tid][m] = t;
        tm2 = tm1;
        tm1 = t;
      }
    }
    __syncthreads();
    if (tid < 128) {
      float s = 0.f;
#pragma unroll 8
      for (int i = 0; i < 128; ++i) s += Tm[i][tid];
      Sm_part[(b * 32 + chunk) * NN + tid] = s;
    }
  }
}

// ---------------------------------------------------------------------------
// Kernel B (kv+attn, all-MFMA). One block per 64-row s-chunk of one batch.
//  p0 : stage emb -> bf16 A-frags (LDS, full 64 KB); tid<128 reduce Sm + wq
//  p1 : kv MFMA (M=64 s, N=128 = K||V cols, K=512)
//  p2 : epilogue tanh -> ktB (B-frag, k=h,n=s) / vB (B-frag, k=s,n=h), bf16
//       (alias the dead A_lds region)
//  p3 : GEMM1 MFMA l[j][s] (A=qnA global frags); e=exp(l/8); Z=sum_j wq_j*e
//  p4 : pack e*invZ -> eA (A-frag, m=j,k=s); GEMM2 MFMA -> atomicAdd O fp32
// LDS: [0,65536) A_lds / frag buffers; [65536,69120) reduction tail.
// ---------------------------------------------------------------------------
__global__ __launch_bounds__(256) void kvattn_kernel(
    const float* __restrict__ emb, const float* __restrict__ kb,
    const unsigned int* __restrict__ Wfrag, const unsigned short* __restrict__ qnA,
    const float* __restrict__ Cmat, const float* __restrict__ Sm_part,
    float* __restrict__ O) {
  __shared__ __align__(16) char smem[69120];
  unsigned short* A_lds = (unsigned short*)smem;         // 65536 B (p0/p1)
  unsigned short* ktB = (unsigned short*)smem;           // 8192 B  (p2+)
  unsigned short* vB = (unsigned short*)(smem + 8192);   // 8192 B  (p2+)
  unsigned short* eA = (unsigned short*)(smem + 16384);  // 16384 B (p4)
  float* zred = (float*)(smem + 65536);                  // 64*9 floats (2304 B)
  float* wql = (float*)(smem + 67840);                   // 128 (512 B)
  float* izl = (float*)(smem + 68352);                   // 64  (256 B)
  float* sml = (float*)(smem + 68608);                   // 128 (512 B)

  const int tid = threadIdx.x;
  const int row0 = blockIdx.x * 64;  // [0, B*S)
  const int bb = row0 >> 12;

  // ---- p0: stage A (64 rows x 512 k), fp32 -> bf16 frags ----
#pragma unroll
  for (int mb = 0; mb < 2; ++mb) {
    int m = tid >> 3;  // 0..31 local row
    int c8 = tid & 7;
    const float* src = emb + (size_t)(row0 + mb * 32 + m) * EE;
    unsigned short* dst = A_lds + mb * 16384;
#pragma unroll
    for (int it = 0; it < 16; ++it) {
      int k = (c8 + it * 8) * 4;
      float4 v = *(const float4*)(src + k);
      int kstep = k >> 4;
      int lane = m + 32 * ((k >> 3) & 1);
      int j = k & 7;
      unsigned int lo = (unsigned int)f2b(v.x) | ((unsigned int)f2b(v.y) << 16);
      unsigned int hi = (unsigned int)f2b(v.z) | ((unsigned int)f2b(v.w) << 16);
      *(uint2*)&dst[(kstep * 64 + lane) * 8 + j] = make_uint2(lo, hi);
    }
  }
  // p0b: Sm chunk-reduce (tid<128)
  if (tid < 128) {
    float s = 0.f;
#pragma unroll 8
    for (int c = 0; c < 32; ++c) s += Sm_part[(bb * 32 + c) * NN + tid];
    sml[tid] = s;
  }
  __syncthreads();
  // p0c: wq[j] (tid<128; fp32 — error ~1e-6 rel, audited)
  if (tid < 128) {
    float acc = sml[0] * (1.0f / NN);
    for (int m = 1; m < NN; ++m)
      acc = fmaf(sml[m] * (2.0f / NN), Cmat[m * NN + tid], acc);
    wql[tid] = acc;
  }

  // ---- p1: kv MFMA ----
  const int w = tid >> 6;  // wave 0..3 (0,1=K cols; 2,3=V cols)
  const int lane = tid & 63;
  f32x16 acc0 = {}, acc1 = {};
  const bf16x8* Bf = (const bf16x8*)Wfrag;
#pragma unroll 4
  for (int kstep = 0; kstep < 32; ++kstep) {
    bf16x8 bfr = Bf[(w * 32 + kstep) * 64 + lane];
    bf16x8 a0 = *(const bf16x8*)&A_lds[(kstep * 64 + lane) * 8];
    bf16x8 a1 = *(const bf16x8*)&A_lds[16384 + (kstep * 64 + lane) * 8];
    acc0 = __builtin_amdgcn_mfma_f32_32x32x16_bf16(a0, bfr, acc0, 0, 0, 0);
    acc1 = __builtin_amdgcn_mfma_f32_32x32x16_bf16(a1, bfr, acc1, 0, 0, 0);
  }
  __syncthreads();  // A_lds dead; ktB/vB/eA alias it

  // ---- p2: epilogue -> bf16 B-frags in LDS ----
  {
    const int n = w * 32 + (lane & 31);
    if (w < 2) {  // K half: element (k=h=n, n_dim=s)
      float kbv = kb[n];
      const int ks_h = n >> 4;
      const int off_h = 32 * ((n >> 3) & 1);
      const int jj_h = n & 7;
#pragma unroll
      for (int reg = 0; reg < 16; ++reg) {
        int sl = (reg & 3) + 8 * (reg >> 2) + 4 * (lane >> 5);  // s in [0,32)
        ktB[(ks_h * 64 + sl + off_h) * 8 + jj_h] =
            f2b(fast_tanh(acc0[reg] + kbv));
        ktB[((4 + ks_h) * 64 + sl + off_h) * 8 + jj_h] =
            f2b(fast_tanh(acc1[reg] + kbv));
      }
    } else {  // V half: element (k=s, n_dim=h)
      int h = n - 64;
      const int nb_h = h >> 5;
      const int lm = h & 31;
#pragma unroll
      for (int reg = 0; reg < 16; ++reg) {
        int sl = (reg & 3) + 8 * (reg >> 2) + 4 * (lane >> 5);
        int s1 = sl + 32;
        vB[((nb_h * 4 + (sl >> 4)) * 64 + lm + 32 * ((sl >> 3) & 1)) * 8 +
           (sl & 7)] = f2b(fast_tanh(acc0[reg]));
        vB[((nb_h * 4 + (s1 >> 4)) * 64 + lm + 32 * ((s1 >> 3) & 1)) * 8 +
           (s1 & 7)] = f2b(fast_tanh(acc1[reg]));
      }
    }
  }
  __syncthreads();

  // ---- p3: GEMM1 MFMA: l[j][s], j-block = w ----
  f32x16 l0 = {}, l1 = {};
#pragma unroll
  for (int ks = 0; ks < 4; ++ks) {
    bf16x8 a = *(const bf16x8*)(qnA + ((w * 4 + ks) * 64 + lane) * 8);
    bf16x8 b0 = *(const bf16x8*)&ktB[(ks * 64 + lane) * 8];
    bf16x8 b1 = *(const bf16x8*)&ktB[((4 + ks) * 64 + lane) * 8];
    l0 = __builtin_amdgcn_mfma_f32_32x32x16_bf16(a, b0, l0, 0, 0, 0);
    l1 = __builtin_amdgcn_mfma_f32_32x32x16_bf16(a, b1, l1, 0, 0, 0);
  }
  // exp + Z partials (j = w*32 + (reg&3)+8*(reg>>2)+4*(lane>>5))
  float e0[16], e1[16];
  float zp0 = 0.f, zp1 = 0.f;
#pragma unroll
  for (int r = 0; r < 4; ++r) {
    float4 wq4 = *(const float4*)&wql[w * 32 + 8 * r + 4 * (lane >> 5)];
    float wa[4] = {wq4.x, wq4.y, wq4.z, wq4.w};
#pragma unroll
    for (int c = 0; c < 4; ++c) {
      int reg = 4 * r + c;
      e0[reg] = __expf(l0[reg] * 0.125f);
      e1[reg] = __expf(l1[reg] * 0.125f);
      zp0 = fmaf(wa[c], e0[reg], zp0);
      zp1 = fmaf(wa[c], e1[reg], zp1);
    }
  }
  zred[(lane & 31) * 9 + w * 2 + (lane >> 5)] = zp0;
  zred[(32 + (lane & 31)) * 9 + w * 2 + (lane >> 5)] = zp1;
  __syncthreads();
  if (tid < 64) {
    float sum = 0.f;
#pragma unroll
    for (int k = 0; k < 8; ++k) sum += zred[tid * 9 + k];
    izl[tid] = 1.0f / sum;
  }
  __syncthreads();

  // ---- p4: pack e*invZ -> eA (A-frag: m=j, k=s), then GEMM2 MFMA ----
  {
    const int sA = lane & 31, sB = 32 + (lane & 31);
    const float izA = izl[sA], izB = izl[sB];
    const int ksA = sA >> 4, oA = 32 * ((sA >> 3) & 1), jA = sA & 7;
    const int ksB = sB >> 4, oB = 32 * ((sB >> 3) & 1), jB = sB & 7;
#pragma unroll
    for (int reg = 0; reg < 16; ++reg) {
      int jl = (reg & 3) + 8 * (reg >> 2) + 4 * (lane >> 5);  // j & 31
      eA[((w * 4 + ksA) * 64 + jl + oA) * 8 + jA] = f2b(e0[reg] * izA);
      eA[((w * 4 + ksB) * 64 + jl + oB) * 8 + jB] = f2b(e1[reg] * izB);
    }
  }
  __syncthreads();
  f32x16 o0 = {}, o1 = {};
#pragma unroll
  for (int ks = 0; ks < 4; ++ks) {
    bf16x8 a = *(const bf16x8*)&eA[((w * 4 + ks) * 64 + lane) * 8];
    bf16x8 b0 = *(const bf16x8*)&vB[(ks * 64 + lane) * 8];
    bf16x8 b1 = *(const bf16x8*)&vB[((4 + ks) * 64 + lane) * 8];
    o0 = __builtin_amdgcn_mfma_f32_32x32x16_bf16(a, b0, o0, 0, 0, 0);
    o1 = __builtin_amdgcn_mfma_f32_32x32x16_bf16(a, b1, o1, 0, 0, 0);
  }
  // R11: atomic s-chunk reduction straight into O[b][j][h] (device-scope
  // fp32 add; unique (j,h) per lane within a block -> contention is only
  // the 64-way cross-block reduction spread over time).
  float* op = O + (size_t)bb * (NN * HH);
  const int h0 = lane & 31, h1 = 32 + (lane & 31);
#pragma unroll
  for (int reg = 0; reg < 16; ++reg) {
    int j = w * 32 + (reg & 3) + 8 * (reg >> 2) + 4 * (lane >> 5);
    atomicAdd(&op[j * HH + h0], o0[reg]);
    atomicAdd(&op[j * HH + h1], o1[reg]);
  }
}

// ---------------------------------------------------------------------------
// Kernel C (ynode+coef+final fused): 64 blocks x 256 threads.
//  head: ynode[b][j] = sum_h tanh(O[b][j][h])*pw[h] + pb  (thread=(j,half),
//        32 KB L2 read per block, pair-combine via shfl_xor)
//  then: recompute coef[b] in LDS (double-acc DCT, redundant across blocks —
//        trivial), then Clenshaw per element.
// ---------------------------------------------------------------------------
__global__ __launch_bounds__(256) void final_kernel(
    const float* __restrict__ x, const float* __restrict__ O,
    const float* __restrict__ pw, const float* __restrict__ pb,
    const float* __restrict__ Cmat, float* __restrict__ y) {
  const int idx = blockIdx.x * 256 + threadIdx.x;  // [0, B*T)
  const int b = idx >> 12;
  __shared__ float yl[NN];
  __shared__ float c[NN];
  // ---- ynode phase ----
  {
    const int j = threadIdx.x >> 1;
    const int half = threadIdx.x & 1;
    const float4* Ov =
        (const float4*)(O + ((size_t)(b * NN + j) * HH + half * 32));
    const float4* pwv = (const float4*)(pw + half * 32);
    float s = 0.f;
#pragma unroll
    for (int q = 0; q < 8; ++q) {
      float4 ov = Ov[q];
      float4 pv = pwv[q];
      s += fast_tanh(ov.x) * pv.x + fast_tanh(ov.y) * pv.y +
           fast_tanh(ov.z) * pv.z + fast_tanh(ov.w) * pv.w;
    }
    s += __shfl_xor(s, 1, 64);
    if (half == 0) yl[j] = s + pb[0];
  }
  __syncthreads();
  if (threadIdx.x < NN) {
    int m = threadIdx.x;
    double acc = 0.0;
#pragma unroll 8
    for (int j = 0; j < NN; ++j)
      acc += (double)yl[j] * (double)Cmat[m * NN + j];
    c[m] = (float)(acc * ((m == 0 ? 1.0 : 2.0) / NN));
  }
  __syncthreads();
  float xf = x[idx] * (1.0f / XR);
  xf = fminf(1.0f, fmaxf(-1.0f, xf));
  double xh = (double)xf;
  double b1 = 0.0, b2 = 0.0;
  for (int m = NN - 1; m >= 1; --m) {
    double t = fma(2.0 * xh, b1, (double)c[m] - b2);
    b2 = b1;
    b1 = t;
  }
  y[idx] = (float)fma(xh, b1, (double)c[0] - b2);
}

extern "C" void kernel_launch(void* const* d_in, const int* in_sizes, int n_in,
                              void* d_out, int out_size, void* d_ws,
                              size_t ws_size, hipStream_t stream) {
  const float* x = (const float*)d_in[0];
  const float* emb = (const float*)d_in[1];
  const float* kw = (const float*)d_in[2];
  const float* kb = (const float*)d_in[3];
  const float* qw = (const float*)d_in[4];
  const float* qb = (const float*)d_in[5];
  const float* vw = (const float*)d_in[6];
  const float* pw = (const float*)d_in[7];
  const float* pb = (const float*)d_in[8];

  float* ws = (float*)d_ws;
  float* O = ws;                                          // 32768 floats
  float* Cmat = ws + 32768;                               // 16384
  unsigned short* qnA = (unsigned short*)(Cmat + 16384);  // 4096 float-slots
  unsigned int* Wfrag = (unsigned int*)(Cmat + 16384 + 4096);  // 32768 slots
  float* Sm_part = (float*)(Wfrag + 32768);               // 16384
  float* y = (float*)d_out;

  prep_sm_kernel<<<288, 256, 0, stream>>>(kw, vw, qw, qb, x, Wfrag, Cmat, qnA,
                                          Sm_part, O);
  kvattn_kernel<<<BB * SS / 64, 256, 0, stream>>>(emb, kb, Wfrag, qnA, Cmat,
                                                  Sm_part, O);
  final_kernel<<<BB * TT / 256, 256, 0, stream>>>(x, O, pw, pb, Cmat, y);
}

// Round 2
// 117.725 us; speedup vs baseline: 1.1412x; 1.0774x over previous
//
#include <hip/hip_runtime.h>
#include <math.h>

// Problem constants (fixed by the reference setup_inputs)
#define BB 4
#define TT 4096
#define SS 4096
#define EE 512
#define HH 64
#define NN 128          // Chebyshev nodes / polynomial degree
#define XR 6.0f         // interpolation half-range for x

// Workspace layout (floats), NO aliasing (~410 KB):
//  O      : [B][N][H]   ws + 0      (32768)  atomic fp32 accumulator (zeroed by prep)
//  Cmat   : [N][N]      ws + 32768  (16384)
//  qnA    : bf16 A-frags +49152     (4096 float-slots = 8192 bf16)
//  Wfrag  : bf16 B-frags +53248     (32768 float-slots = 65536 bf16)
//  Sm_part: [B][32][N]  +86016     (16384)
//
// Session lessons (measured):
//  R9 : cooperative grid.sync() ~50 us each on MI355X. Dispatch boundary ~5 us.
//  R10: kvattn grid = 256 blocks on 256 CUs -> occupancy GRID-limited at
//       1 block/CU (1 wave/SIMD); splitting to 512 blocks + LDS reduce cost
//       +2.7 us. Keep 64 KB staging, 256 blocks.
//  R11: atomicAdd O fold (-1 kernel), Chebyshev-recurrence Sm, fast_tanh:
//       134.4 -> 126.8 us, absmax unchanged.
//  R12 (this round): kill exposed-latency chains at 1 wave/SIMD:
//       - p0c wq dot: 4 independent accumulators + unroll (was a single
//         serial fmaf chain with an L2 load per iter -> up to ~10 us).
//       - p0 staging: batch 16 float4 loads into regs, then convert+store
//         (was load/convert/store per iter -> worst case 32 exposed HBM lats).
//       - prep: fp64 cos -> integer mod-512 reduction + fp32 cosf (exact
//         range reduction; values only need ~1e-6).
//       - prep grid 288 -> 256 (qnA branch folded into Cmat blocks): one
//         scheduling round.

typedef __attribute__((ext_vector_type(8))) __bf16 bf16x8;
typedef __attribute__((ext_vector_type(16))) float f32x16;

__device__ __forceinline__ unsigned short f2b(float f) {
  unsigned int u = __float_as_uint(f);
  return (unsigned short)((u + 0x7FFFu + ((u >> 16) & 1u)) >> 16);  // RNE
}

// tanh via HW exp+rcp: rel err ~1e-6, ~5 VALU ops vs ~25 for ocml tanhf.
__device__ __forceinline__ float fast_tanh(float v) {
  float e = __expf(fminf(60.0f, 2.0f * v));
  return (e - 1.0f) * __builtin_amdgcn_rcpf(e + 1.0f);
}

// ---------------------------------------------------------------------------
// Kernel A (prep+sm fused), 256 blocks:
//   blocks [0,64)   : Wfrag pack (kw||vw fp32 -> MFMA B-frag bf16)
//   blocks [64,128) : Cmat[m][j] = cos(m*pi*(j+.5)/N) via int mod-512 + cosf;
//                     blocks [64,96) also qnA A-frags + zero O (128 KB)
//   blocks [128,256): Sm_part[b][chunk][m] = sum_{128 t} T_m(xhat_t)
//                     via 1-FMA Chebyshev recurrence + LDS transpose-sum
// ---------------------------------------------------------------------------
__global__ __launch_bounds__(256) void prep_sm_kernel(
    const float* __restrict__ kw, const float* __restrict__ vw,
    const float* __restrict__ qw, const float* __restrict__ qb,
    const float* __restrict__ x, unsigned int* __restrict__ Wfrag,
    float* __restrict__ Cmat, unsigned short* __restrict__ qnA,
    float* __restrict__ Sm_part, float* __restrict__ Oz) {
  const int blk = blockIdx.x;
  if (blk < 64) {
    // Wfrag pack: ((nblk*32 + kstep)*64 + lane)*8 + j  (bf16 units)
    int idx = blk * 256 + threadIdx.x;  // [0, 16384)
    int jq = idx & 1;
    int l = (idx >> 1) & 63;
    int ks = (idx >> 7) & 31;
    int nb = idx >> 12;
    int n = nb * 32 + (l & 31);
    int k = ks * 16 + (l >> 5) * 8 + jq * 4;
    const float* row = (n < HH) ? (kw + n * EE + k) : (vw + (n - HH) * EE + k);
    float4 wv = *(const float4*)row;
    Wfrag[idx * 2] = (unsigned int)f2b(wv.x) | ((unsigned int)f2b(wv.y) << 16);
    Wfrag[idx * 2 + 1] =
        (unsigned int)f2b(wv.z) | ((unsigned int)f2b(wv.w) << 16);
  } else if (blk < 128) {
    int idx = (blk - 64) * 256 + threadIdx.x;  // [0, N*N)
    int m = idx >> 7;
    int j = idx & (NN - 1);
    // angle = pi*m*(2j+1)/256; exact reduction mod 2*pi (512 units of pi/256)
    int k = (m * (2 * j + 1)) & 511;
    if (k >= 256) k -= 512;
    Cmat[idx] = cosf((float)k * (float)(M_PI / 256.0));
    // zero the atomic O accumulator: 8192 float4 = 128 KB
    if (idx < 8192) ((float4*)Oz)[idx] = make_float4(0.f, 0.f, 0.f, 0.f);
    if (idx < 8192) {
      int h = idx & 63;
      int j2 = idx >> 6;  // [0,128)
      float th = (float)M_PI * ((float)j2 + 0.5f) * (1.0f / NN);
      float xj = XR * cosf(th);
      float val = tanhf(fmaf(xj, qw[h], qb[h]));
      // A-frag position for element (m=j2, k=h):
      int pos =
          (((j2 >> 5) * 4 + (h >> 4)) * 64 + (j2 & 31) + 32 * ((h >> 3) & 1)) *
              8 +
          (h & 7);
      qnA[pos] = f2b(val);
    }
  } else {
    // Sm via Chebyshev recurrence: cos(m*acos(xhat)) == T_m(xhat), exactly.
    // Tm[i][m], padded to 129 -> both row-write and column-read conflict-free.
    __shared__ float Tm[128][NN + 1];  // 66048 B
    int blk2 = blk - 128;  // [0,128)
    int b = blk2 >> 5;
    int chunk = blk2 & 31;
    int tid = threadIdx.x;
    if (tid < 128) {
      float xh = x[b * TT + chunk * 128 + tid] * (1.0f / XR);
      xh = fminf(1.0f, fmaxf(-1.0f, xh));
      Tm[tid][0] = 1.0f;
      Tm[tid][1] = xh;
      float x2 = 2.0f * xh;
      float tm2 = 1.0f, tm1 = xh;
#pragma unroll 6
      for (int m = 2; m < NN; ++m) {
        float t = fmaf(x2, tm1, -tm2);
        Tm[tid][m] = t;
        tm2 = tm1;
        tm1 = t;
      }
    }
    __syncthreads();
    if (tid < 128) {
      float s = 0.f;
#pragma unroll 8
      for (int i = 0; i < 128; ++i) s += Tm[i][tid];
      Sm_part[(b * 32 + chunk) * NN + tid] = s;
    }
  }
}

// ---------------------------------------------------------------------------
// Kernel B (kv+attn, all-MFMA). One block per 64-row s-chunk of one batch.
//  p0 : stage emb -> bf16 A-frags (LDS, full 64 KB); tid<128 reduce Sm + wq
//  p1 : kv MFMA (M=64 s, N=128 = K||V cols, K=512)
//  p2 : epilogue tanh -> ktB (B-frag, k=h,n=s) / vB (B-frag, k=s,n=h), bf16
//  p3 : GEMM1 MFMA l[j][s] (A=qnA global frags); e=exp(l/8); Z=sum_j wq_j*e
//  p4 : pack e*invZ -> eA (A-frag, m=j,k=s); GEMM2 MFMA -> atomicAdd O fp32
// LDS: [0,65536) A_lds / frag buffers; [65536,69120) reduction tail.
// ---------------------------------------------------------------------------
__global__ __launch_bounds__(256) void kvattn_kernel(
    const float* __restrict__ emb, const float* __restrict__ kb,
    const unsigned int* __restrict__ Wfrag, const unsigned short* __restrict__ qnA,
    const float* __restrict__ Cmat, const float* __restrict__ Sm_part,
    float* __restrict__ O) {
  __shared__ __align__(16) char smem[69120];
  unsigned short* A_lds = (unsigned short*)smem;         // 65536 B (p0/p1)
  unsigned short* ktB = (unsigned short*)smem;           // 8192 B  (p2+)
  unsigned short* vB = (unsigned short*)(smem + 8192);   // 8192 B  (p2+)
  unsigned short* eA = (unsigned short*)(smem + 16384);  // 16384 B (p4)
  float* zred = (float*)(smem + 65536);                  // 64*9 floats (2304 B)
  float* wql = (float*)(smem + 67840);                   // 128 (512 B)
  float* izl = (float*)(smem + 68352);                   // 64  (256 B)
  float* sml = (float*)(smem + 68608);                   // 128 (512 B)

  const int tid = threadIdx.x;
  const int row0 = blockIdx.x * 64;  // [0, B*S)
  const int bb = row0 >> 12;

  // ---- p0: stage A (64 rows x 512 k), fp32 -> bf16 frags ----
  // R12: batch 16 loads into regs first so HBM latency is exposed ~2x,
  // not up to 32x (1 wave/SIMD -> nothing else hides it).
#pragma unroll
  for (int mb = 0; mb < 2; ++mb) {
    int m = tid >> 3;  // 0..31 local row
    int c8 = tid & 7;
    const float* src = emb + (size_t)(row0 + mb * 32 + m) * EE;
    unsigned short* dst = A_lds + mb * 16384;
    float4 buf[16];
#pragma unroll
    for (int it = 0; it < 16; ++it) buf[it] = *(const float4*)(src + (c8 + it * 8) * 4);
#pragma unroll
    for (int it = 0; it < 16; ++it) {
      int k = (c8 + it * 8) * 4;
      float4 v = buf[it];
      int kstep = k >> 4;
      int lane = m + 32 * ((k >> 3) & 1);
      int j = k & 7;
      unsigned int lo = (unsigned int)f2b(v.x) | ((unsigned int)f2b(v.y) << 16);
      unsigned int hi = (unsigned int)f2b(v.z) | ((unsigned int)f2b(v.w) << 16);
      *(uint2*)&dst[(kstep * 64 + lane) * 8 + j] = make_uint2(lo, hi);
    }
  }
  // p0b: Sm chunk-reduce (tid<128); fold DCT scale into sml
  if (tid < 128) {
    float s = 0.f;
#pragma unroll 8
    for (int c = 0; c < 32; ++c) s += Sm_part[(bb * 32 + c) * NN + tid];
    sml[tid] = s * ((tid == 0) ? (1.0f / NN) : (2.0f / NN));
  }
  __syncthreads();
  // p0c: wq[j] dot (tid<128). R12: 4 independent accumulators so the 128
  // L2 loads of Cmat pipeline instead of serializing behind one fmaf chain.
  if (tid < 128) {
    float a0 = 0.f, a1 = 0.f, a2 = 0.f, a3 = 0.f;
#pragma unroll
    for (int m = 0; m < NN; m += 4) {
      a0 = fmaf(sml[m], Cmat[m * NN + tid], a0);
      a1 = fmaf(sml[m + 1], Cmat[(m + 1) * NN + tid], a1);
      a2 = fmaf(sml[m + 2], Cmat[(m + 2) * NN + tid], a2);
      a3 = fmaf(sml[m + 3], Cmat[(m + 3) * NN + tid], a3);
    }
    wql[tid] = (a0 + a1) + (a2 + a3);
  }

  // ---- p1: kv MFMA ----
  const int w = tid >> 6;  // wave 0..3 (0,1=K cols; 2,3=V cols)
  const int lane = tid & 63;
  f32x16 acc0 = {}, acc1 = {};
  const bf16x8* Bf = (const bf16x8*)Wfrag;
#pragma unroll 4
  for (int kstep = 0; kstep < 32; ++kstep) {
    bf16x8 bfr = Bf[(w * 32 + kstep) * 64 + lane];
    bf16x8 a0 = *(const bf16x8*)&A_lds[(kstep * 64 + lane) * 8];
    bf16x8 a1 = *(const bf16x8*)&A_lds[16384 + (kstep * 64 + lane) * 8];
    acc0 = __builtin_amdgcn_mfma_f32_32x32x16_bf16(a0, bfr, acc0, 0, 0, 0);
    acc1 = __builtin_amdgcn_mfma_f32_32x32x16_bf16(a1, bfr, acc1, 0, 0, 0);
  }
  __syncthreads();  // A_lds dead; ktB/vB/eA alias it

  // ---- p2: epilogue -> bf16 B-frags in LDS ----
  {
    const int n = w * 32 + (lane & 31);
    if (w < 2) {  // K half: element (k=h=n, n_dim=s)
      float kbv = kb[n];
      const int ks_h = n >> 4;
      const int off_h = 32 * ((n >> 3) & 1);
      const int jj_h = n & 7;
#pragma unroll
      for (int reg = 0; reg < 16; ++reg) {
        int sl = (reg & 3) + 8 * (reg >> 2) + 4 * (lane >> 5);  // s in [0,32)
        ktB[(ks_h * 64 + sl + off_h) * 8 + jj_h] =
            f2b(fast_tanh(acc0[reg] + kbv));
        ktB[((4 + ks_h) * 64 + sl + off_h) * 8 + jj_h] =
            f2b(fast_tanh(acc1[reg] + kbv));
      }
    } else {  // V half: element (k=s, n_dim=h)
      int h = n - 64;
      const int nb_h = h >> 5;
      const int lm = h & 31;
#pragma unroll
      for (int reg = 0; reg < 16; ++reg) {
        int sl = (reg & 3) + 8 * (reg >> 2) + 4 * (lane >> 5);
        int s1 = sl + 32;
        vB[((nb_h * 4 + (sl >> 4)) * 64 + lm + 32 * ((sl >> 3) & 1)) * 8 +
           (sl & 7)] = f2b(fast_tanh(acc0[reg]));
        vB[((nb_h * 4 + (s1 >> 4)) * 64 + lm + 32 * ((s1 >> 3) & 1)) * 8 +
           (s1 & 7)] = f2b(fast_tanh(acc1[reg]));
      }
    }
  }
  __syncthreads();

  // ---- p3: GEMM1 MFMA: l[j][s], j-block = w ----
  f32x16 l0 = {}, l1 = {};
#pragma unroll
  for (int ks = 0; ks < 4; ++ks) {
    bf16x8 a = *(const bf16x8*)(qnA + ((w * 4 + ks) * 64 + lane) * 8);
    bf16x8 b0 = *(const bf16x8*)&ktB[(ks * 64 + lane) * 8];
    bf16x8 b1 = *(const bf16x8*)&ktB[((4 + ks) * 64 + lane) * 8];
    l0 = __builtin_amdgcn_mfma_f32_32x32x16_bf16(a, b0, l0, 0, 0, 0);
    l1 = __builtin_amdgcn_mfma_f32_32x32x16_bf16(a, b1, l1, 0, 0, 0);
  }
  // exp + Z partials (j = w*32 + (reg&3)+8*(reg>>2)+4*(lane>>5))
  float e0[16], e1[16];
  float zp0 = 0.f, zp1 = 0.f;
#pragma unroll
  for (int r = 0; r < 4; ++r) {
    float4 wq4 = *(const float4*)&wql[w * 32 + 8 * r + 4 * (lane >> 5)];
    float wa[4] = {wq4.x, wq4.y, wq4.z, wq4.w};
#pragma unroll
    for (int c = 0; c < 4; ++c) {
      int reg = 4 * r + c;
      e0[reg] = __expf(l0[reg] * 0.125f);
      e1[reg] = __expf(l1[reg] * 0.125f);
      zp0 = fmaf(wa[c], e0[reg], zp0);
      zp1 = fmaf(wa[c], e1[reg], zp1);
    }
  }
  zred[(lane & 31) * 9 + w * 2 + (lane >> 5)] = zp0;
  zred[(32 + (lane & 31)) * 9 + w * 2 + (lane >> 5)] = zp1;
  __syncthreads();
  if (tid < 64) {
    float sum = 0.f;
#pragma unroll
    for (int k = 0; k < 8; ++k) sum += zred[tid * 9 + k];
    izl[tid] = 1.0f / sum;
  }
  __syncthreads();

  // ---- p4: pack e*invZ -> eA (A-frag: m=j, k=s), then GEMM2 MFMA ----
  {
    const int sA = lane & 31, sB = 32 + (lane & 31);
    const float izA = izl[sA], izB = izl[sB];
    const int ksA = sA >> 4, oA = 32 * ((sA >> 3) & 1), jA = sA & 7;
    const int ksB = sB >> 4, oB = 32 * ((sB >> 3) & 1), jB = sB & 7;
#pragma unroll
    for (int reg = 0; reg < 16; ++reg) {
      int jl = (reg & 3) + 8 * (reg >> 2) + 4 * (lane >> 5);  // j & 31
      eA[((w * 4 + ksA) * 64 + jl + oA) * 8 + jA] = f2b(e0[reg] * izA);
      eA[((w * 4 + ksB) * 64 + jl + oB) * 8 + jB] = f2b(e1[reg] * izB);
    }
  }
  __syncthreads();
  f32x16 o0 = {}, o1 = {};
#pragma unroll
  for (int ks = 0; ks < 4; ++ks) {
    bf16x8 a = *(const bf16x8*)&eA[((w * 4 + ks) * 64 + lane) * 8];
    bf16x8 b0 = *(const bf16x8*)&vB[(ks * 64 + lane) * 8];
    bf16x8 b1 = *(const bf16x8*)&vB[((4 + ks) * 64 + lane) * 8];
    o0 = __builtin_amdgcn_mfma_f32_32x32x16_bf16(a, b0, o0, 0, 0, 0);
    o1 = __builtin_amdgcn_mfma_f32_32x32x16_bf16(a, b1, o1, 0, 0, 0);
  }
  // atomic s-chunk reduction straight into O[b][j][h] (device-scope fp32
  // add; unique (j,h) per lane within a block -> contention is only the
  // 64-way cross-block reduction spread over time).
  float* op = O + (size_t)bb * (NN * HH);
  const int h0 = lane & 31, h1 = 32 + (lane & 31);
#pragma unroll
  for (int reg = 0; reg < 16; ++reg) {
    int j = w * 32 + (reg & 3) + 8 * (reg >> 2) + 4 * (lane >> 5);
    atomicAdd(&op[j * HH + h0], o0[reg]);
    atomicAdd(&op[j * HH + h1], o1[reg]);
  }
}

// ---------------------------------------------------------------------------
// Kernel C (ynode+coef+final fused): 64 blocks x 256 threads.
//  head: ynode[b][j] = sum_h tanh(O[b][j][h])*pw[h] + pb  (thread=(j,half),
//        32 KB L2 read per block, pair-combine via shfl_xor)
//  then: recompute coef[b] in LDS (double-acc DCT, redundant across blocks —
//        trivial), then Clenshaw per element.
// ---------------------------------------------------------------------------
__global__ __launch_bounds__(256) void final_kernel(
    const float* __restrict__ x, const float* __restrict__ O,
    const float* __restrict__ pw, const float* __restrict__ pb,
    const float* __restrict__ Cmat, float* __restrict__ y) {
  const int idx = blockIdx.x * 256 + threadIdx.x;  // [0, B*T)
  const int b = idx >> 12;
  __shared__ float yl[NN];
  __shared__ float c[NN];
  // ---- ynode phase ----
  {
    const int j = threadIdx.x >> 1;
    const int half = threadIdx.x & 1;
    const float4* Ov =
        (const float4*)(O + ((size_t)(b * NN + j) * HH + half * 32));
    const float4* pwv = (const float4*)(pw + half * 32);
    float s = 0.f;
#pragma unroll
    for (int q = 0; q < 8; ++q) {
      float4 ov = Ov[q];
      float4 pv = pwv[q];
      s += fast_tanh(ov.x) * pv.x + fast_tanh(ov.y) * pv.y +
           fast_tanh(ov.z) * pv.z + fast_tanh(ov.w) * pv.w;
    }
    s += __shfl_xor(s, 1, 64);
    if (half == 0) yl[j] = s + pb[0];
  }
  __syncthreads();
  if (threadIdx.x < NN) {
    int m = threadIdx.x;
    double acc = 0.0;
#pragma unroll 8
    for (int j = 0; j < NN; ++j)
      acc += (double)yl[j] * (double)Cmat[m * NN + j];
    c[m] = (float)(acc * ((m == 0 ? 1.0 : 2.0) / NN));
  }
  __syncthreads();
  float xf = x[idx] * (1.0f / XR);
  xf = fminf(1.0f, fmaxf(-1.0f, xf));
  double xh = (double)xf;
  double b1 = 0.0, b2 = 0.0;
  for (int m = NN - 1; m >= 1; --m) {
    double t = fma(2.0 * xh, b1, (double)c[m] - b2);
    b2 = b1;
    b1 = t;
  }
  y[idx] = (float)fma(xh, b1, (double)c[0] - b2);
}

extern "C" void kernel_launch(void* const* d_in, const int* in_sizes, int n_in,
                              void* d_out, int out_size, void* d_ws,
                              size_t ws_size, hipStream_t stream) {
  const float* x = (const float*)d_in[0];
  const float* emb = (const float*)d_in[1];
  const float* kw = (const float*)d_in[2];
  const float* kb = (const float*)d_in[3];
  const float* qw = (const float*)d_in[4];
  const float* qb = (const float*)d_in[5];
  const float* vw = (const float*)d_in[6];
  const float* pw = (const float*)d_in[7];
  const float* pb = (const float*)d_in[8];

  float* ws = (float*)d_ws;
  float* O = ws;                                          // 32768 floats
  float* Cmat = ws + 32768;                               // 16384
  unsigned short* qnA = (unsigned short*)(Cmat + 16384);  // 4096 float-slots
  unsigned int* Wfrag = (unsigned int*)(Cmat + 16384 + 4096);  // 32768 slots
  float* Sm_part = (float*)(Wfrag + 32768);               // 16384
  float* y = (float*)d_out;

  prep_sm_kernel<<<256, 256, 0, stream>>>(kw, vw, qw, qb, x, Wfrag, Cmat, qnA,
                                          Sm_part, O);
  kvattn_kernel<<<BB * SS / 64, 256, 0, stream>>>(emb, kb, Wfrag, qnA, Cmat,
                                                  Sm_part, O);
  final_kernel<<<BB * TT / 256, 256, 0, stream>>>(x, O, pw, pb, Cmat, y);
}

// Round 3
// 116.067 us; speedup vs baseline: 1.1575x; 1.0143x over previous
//
#include <hip/hip_runtime.h>
#include <math.h>

// Problem constants (fixed by the reference setup_inputs)
#define BB 4
#define TT 4096
#define SS 4096
#define EE 512
#define HH 64
#define NN 128          // Chebyshev nodes / polynomial degree
#define XR 6.0f         // interpolation half-range for x

// Workspace layout (floats), NO aliasing (~410 KB):
//  O      : [B][N][H]   ws + 0      (32768)  atomic fp32 accumulator (zeroed by prep)
//  Cmat   : [N][N]      ws + 32768  (16384)
//  qnA    : bf16 A-frags +49152     (4096 float-slots = 8192 bf16)
//  Wfrag  : bf16 B-frags +53248     (32768 float-slots = 65536 bf16)
//  Sm_part: [B][32][N]  +86016     (16384)
//
// Session lessons (measured):
//  R9 : cooperative grid.sync() ~50 us each on MI355X. Dispatch boundary ~5 us.
//  R10: kvattn 512-block split + LDS reduce cost +2.7 us. Keep 256 blocks.
//  R11: atomicAdd O fold (-1 kernel), Chebyshev Sm, fast_tanh: 134.4 -> 126.8.
//  R12: killed exposed-latency chains (4-acc wq dot, batched staging loads,
//       fp32 trig, grid 256): 126.8 -> 117.7. Confirms per-block critical
//       path translates ~1:1 (1 block/CU lockstep).
//  R13 (this round): kvattn 256 threads -> 512 (8 waves, 2 waves/SIMD).
//       Same total work; each wave owns one (n-quarter, m-half) so per-wave
//       dependent chains halve and MFMA/VALU from co-resident waves overlap.
//       Only kvattn changed (clean attribution).

typedef __attribute__((ext_vector_type(8))) __bf16 bf16x8;
typedef __attribute__((ext_vector_type(16))) float f32x16;

__device__ __forceinline__ unsigned short f2b(float f) {
  unsigned int u = __float_as_uint(f);
  return (unsigned short)((u + 0x7FFFu + ((u >> 16) & 1u)) >> 16);  // RNE
}

// tanh via HW exp+rcp: rel err ~1e-6, ~5 VALU ops vs ~25 for ocml tanhf.
__device__ __forceinline__ float fast_tanh(float v) {
  float e = __expf(fminf(60.0f, 2.0f * v));
  return (e - 1.0f) * __builtin_amdgcn_rcpf(e + 1.0f);
}

// ---------------------------------------------------------------------------
// Kernel A (prep+sm fused), 256 blocks:
//   blocks [0,64)   : Wfrag pack (kw||vw fp32 -> MFMA B-frag bf16)
//   blocks [64,128) : Cmat[m][j] = cos(m*pi*(j+.5)/N) via int mod-512 + cosf;
//                     blocks [64,96) also qnA A-frags + zero O (128 KB)
//   blocks [128,256): Sm_part[b][chunk][m] = sum_{128 t} T_m(xhat_t)
//                     via 1-FMA Chebyshev recurrence + LDS transpose-sum
// ---------------------------------------------------------------------------
__global__ __launch_bounds__(256) void prep_sm_kernel(
    const float* __restrict__ kw, const float* __restrict__ vw,
    const float* __restrict__ qw, const float* __restrict__ qb,
    const float* __restrict__ x, unsigned int* __restrict__ Wfrag,
    float* __restrict__ Cmat, unsigned short* __restrict__ qnA,
    float* __restrict__ Sm_part, float* __restrict__ Oz) {
  const int blk = blockIdx.x;
  if (blk < 64) {
    // Wfrag pack: ((nblk*32 + kstep)*64 + lane)*8 + j  (bf16 units)
    int idx = blk * 256 + threadIdx.x;  // [0, 16384)
    int jq = idx & 1;
    int l = (idx >> 1) & 63;
    int ks = (idx >> 7) & 31;
    int nb = idx >> 12;
    int n = nb * 32 + (l & 31);
    int k = ks * 16 + (l >> 5) * 8 + jq * 4;
    const float* row = (n < HH) ? (kw + n * EE + k) : (vw + (n - HH) * EE + k);
    float4 wv = *(const float4*)row;
    Wfrag[idx * 2] = (unsigned int)f2b(wv.x) | ((unsigned int)f2b(wv.y) << 16);
    Wfrag[idx * 2 + 1] =
        (unsigned int)f2b(wv.z) | ((unsigned int)f2b(wv.w) << 16);
  } else if (blk < 128) {
    int idx = (blk - 64) * 256 + threadIdx.x;  // [0, N*N)
    int m = idx >> 7;
    int j = idx & (NN - 1);
    // angle = pi*m*(2j+1)/256; exact reduction mod 2*pi (512 units of pi/256)
    int k = (m * (2 * j + 1)) & 511;
    if (k >= 256) k -= 512;
    Cmat[idx] = cosf((float)k * (float)(M_PI / 256.0));
    // zero the atomic O accumulator: 8192 float4 = 128 KB
    if (idx < 8192) ((float4*)Oz)[idx] = make_float4(0.f, 0.f, 0.f, 0.f);
    if (idx < 8192) {
      int h = idx & 63;
      int j2 = idx >> 6;  // [0,128)
      float th = (float)M_PI * ((float)j2 + 0.5f) * (1.0f / NN);
      float xj = XR * cosf(th);
      float val = tanhf(fmaf(xj, qw[h], qb[h]));
      // A-frag position for element (m=j2, k=h):
      int pos =
          (((j2 >> 5) * 4 + (h >> 4)) * 64 + (j2 & 31) + 32 * ((h >> 3) & 1)) *
              8 +
          (h & 7);
      qnA[pos] = f2b(val);
    }
  } else {
    // Sm via Chebyshev recurrence: cos(m*acos(xhat)) == T_m(xhat), exactly.
    // Tm[i][m], padded to 129 -> both row-write and column-read conflict-free.
    __shared__ float Tm[128][NN + 1];  // 66048 B
    int blk2 = blk - 128;  // [0,128)
    int b = blk2 >> 5;
    int chunk = blk2 & 31;
    int tid = threadIdx.x;
    if (tid < 128) {
      float xh = x[b * TT + chunk * 128 + tid] * (1.0f / XR);
      xh = fminf(1.0f, fmaxf(-1.0f, xh));
      Tm[tid][0] = 1.0f;
      Tm[tid][1] = xh;
      float x2 = 2.0f * xh;
      float tm2 = 1.0f, tm1 = xh;
#pragma unroll 6
      for (int m = 2; m < NN; ++m) {
        float t = fmaf(x2, tm1, -tm2);
        Tm[tid][m] = t;
        tm2 = tm1;
        tm1 = t;
      }
    }
    __syncthreads();
    if (tid < 128) {
      float s = 0.f;
#pragma unroll 8
      for (int i = 0; i < 128; ++i) s += Tm[i][tid];
      Sm_part[(b * 32 + chunk) * NN + tid] = s;
    }
  }
}

// ---------------------------------------------------------------------------
// Kernel B (kv+attn, all-MFMA). One block (512 thr, 8 waves) per 64-row
// s-chunk of one batch. Wave w8 = (mh = w8>>2 [m/s-half], w = w8&3 [quarter]).
//  p0 : stage emb -> bf16 A-frags (LDS, full 64 KB); tid<128 reduce Sm + wq
//  p1 : kv MFMA; wave (w,mh): acc = emb[mh-half] x W[quarter w] over K=512
//  p2 : epilogue tanh -> ktB (B-frag, k=h,n=s) / vB (B-frag, k=s,n=h), bf16
//  p3 : GEMM1 l[j][s]: wave (jb=w, sh=mh); e=exp(l/8); Z=sum_j wq_j*e
//  p4 : pack e*invZ -> eA (A-frag, m=j,k=s); GEMM2 wave (jb=w, hh=mh)
//       -> atomicAdd O fp32
// LDS: [0,65536) A_lds / frag buffers; [65536,69120) reduction tail.
// ---------------------------------------------------------------------------
__global__ __launch_bounds__(512) void kvattn_kernel(
    const float* __restrict__ emb, const float* __restrict__ kb,
    const unsigned int* __restrict__ Wfrag, const unsigned short* __restrict__ qnA,
    const float* __restrict__ Cmat, const float* __restrict__ Sm_part,
    float* __restrict__ O) {
  __shared__ __align__(16) char smem[69120];
  unsigned short* A_lds = (unsigned short*)smem;         // 65536 B (p0/p1)
  unsigned short* ktB = (unsigned short*)smem;           // 8192 B  (p2+)
  unsigned short* vB = (unsigned short*)(smem + 8192);   // 8192 B  (p2+)
  unsigned short* eA = (unsigned short*)(smem + 16384);  // 16384 B (p4)
  float* zred = (float*)(smem + 65536);                  // 64*9 floats (2304 B)
  float* wql = (float*)(smem + 67840);                   // 128 (512 B)
  float* izl = (float*)(smem + 68352);                   // 64  (256 B)
  float* sml = (float*)(smem + 68608);                   // 128 (512 B)

  const int tid = threadIdx.x;
  const int row0 = blockIdx.x * 64;  // [0, B*S)
  const int bb = row0 >> 12;

  // ---- p0: stage A (64 rows x 512 k), fp32 -> bf16 frags ----
  // 512 threads: 8 threads/row, 16 float4/thread, batched loads first.
  {
    int m = tid >> 3;  // 0..63 local row
    int c8 = tid & 7;
    const float* src = emb + (size_t)(row0 + m) * EE;
    unsigned short* dst = A_lds + (m >> 5) * 16384;
    int ml = m & 31;
    float4 buf[16];
#pragma unroll
    for (int it = 0; it < 16; ++it)
      buf[it] = *(const float4*)(src + (c8 + it * 8) * 4);
#pragma unroll
    for (int it = 0; it < 16; ++it) {
      int k = (c8 + it * 8) * 4;
      float4 v = buf[it];
      int kstep = k >> 4;
      int lane_f = ml + 32 * ((k >> 3) & 1);
      int j = k & 7;
      unsigned int lo = (unsigned int)f2b(v.x) | ((unsigned int)f2b(v.y) << 16);
      unsigned int hi = (unsigned int)f2b(v.z) | ((unsigned int)f2b(v.w) << 16);
      *(uint2*)&dst[(kstep * 64 + lane_f) * 8 + j] = make_uint2(lo, hi);
    }
  }
  // p0b: Sm chunk-reduce (tid<128); fold DCT scale into sml
  if (tid < 128) {
    float s = 0.f;
#pragma unroll 8
    for (int c = 0; c < 32; ++c) s += Sm_part[(bb * 32 + c) * NN + tid];
    sml[tid] = s * ((tid == 0) ? (1.0f / NN) : (2.0f / NN));
  }
  __syncthreads();
  // p0c: wq[j] dot (tid<128), 4 independent accumulators.
  if (tid < 128) {
    float a0 = 0.f, a1 = 0.f, a2 = 0.f, a3 = 0.f;
#pragma unroll
    for (int m = 0; m < NN; m += 4) {
      a0 = fmaf(sml[m], Cmat[m * NN + tid], a0);
      a1 = fmaf(sml[m + 1], Cmat[(m + 1) * NN + tid], a1);
      a2 = fmaf(sml[m + 2], Cmat[(m + 2) * NN + tid], a2);
      a3 = fmaf(sml[m + 3], Cmat[(m + 3) * NN + tid], a3);
    }
    wql[tid] = (a0 + a1) + (a2 + a3);
  }

  // ---- p1: kv MFMA. wave (w = n-quarter, mh = m-half), one 16-reg acc ----
  const int w8 = tid >> 6;   // wave 0..7
  const int lane = tid & 63;
  const int w = w8 & 3;      // n-quarter (0,1=K cols; 2,3=V cols)
  const int mh = w8 >> 2;    // m-half (s rows mh*32..mh*32+31)
  f32x16 acc = {};
  const bf16x8* Bf = (const bf16x8*)Wfrag;
  const unsigned short* Ah = A_lds + mh * 16384;
#pragma unroll 4
  for (int kstep = 0; kstep < 32; ++kstep) {
    bf16x8 bfr = Bf[(w * 32 + kstep) * 64 + lane];
    bf16x8 a = *(const bf16x8*)&Ah[(kstep * 64 + lane) * 8];
    acc = __builtin_amdgcn_mfma_f32_32x32x16_bf16(a, bfr, acc, 0, 0, 0);
  }
  __syncthreads();  // A_lds dead; ktB/vB/eA alias it

  // ---- p2: epilogue -> bf16 B-frags in LDS ----
  // acc element: (s = mh*32 + sl(reg,lane), n = w*32 + (lane&31))
  {
    const int n = w * 32 + (lane & 31);
    if (w < 2) {  // K half: dest element (k=h=n, n_dim=s)
      float kbv = kb[n];
      const int ks_h = n >> 4;
      const int off_h = 32 * ((n >> 3) & 1);
      const int jj_h = n & 7;
#pragma unroll
      for (int reg = 0; reg < 16; ++reg) {
        int sl = (reg & 3) + 8 * (reg >> 2) + 4 * (lane >> 5);  // s in half
        ktB[((mh * 4 + ks_h) * 64 + sl + off_h) * 8 + jj_h] =
            f2b(fast_tanh(acc[reg] + kbv));
      }
    } else {  // V half: dest element (k=s, n_dim=h)
      int h = n - 64;
      const int nb_h = h >> 5;
      const int lm = h & 31;
#pragma unroll
      for (int reg = 0; reg < 16; ++reg) {
        int sl = (reg & 3) + 8 * (reg >> 2) + 4 * (lane >> 5);
        int s = mh * 32 + sl;
        vB[((nb_h * 4 + (s >> 4)) * 64 + lm + 32 * ((s >> 3) & 1)) * 8 +
           (s & 7)] = f2b(fast_tanh(acc[reg]));
      }
    }
  }
  __syncthreads();

  // ---- p3: GEMM1 l[j][s]: wave (jb = w, sh = mh) ----
  f32x16 l0 = {};
#pragma unroll
  for (int ks = 0; ks < 4; ++ks) {
    bf16x8 a = *(const bf16x8*)(qnA + ((w * 4 + ks) * 64 + lane) * 8);
    bf16x8 b0 = *(const bf16x8*)&ktB[((mh * 4 + ks) * 64 + lane) * 8];
    l0 = __builtin_amdgcn_mfma_f32_32x32x16_bf16(a, b0, l0, 0, 0, 0);
  }
  // exp + Z partials (j = w*32 + (reg&3)+8*(reg>>2)+4*(lane>>5), s fixed/lane)
  float e0[16];
  float zp = 0.f;
#pragma unroll
  for (int r = 0; r < 4; ++r) {
    float4 wq4 = *(const float4*)&wql[w * 32 + 8 * r + 4 * (lane >> 5)];
    float wa[4] = {wq4.x, wq4.y, wq4.z, wq4.w};
#pragma unroll
    for (int c = 0; c < 4; ++c) {
      int reg = 4 * r + c;
      e0[reg] = __expf(l0[reg] * 0.125f);
      zp = fmaf(wa[c], e0[reg], zp);
    }
  }
  zred[(mh * 32 + (lane & 31)) * 9 + w * 2 + (lane >> 5)] = zp;
  __syncthreads();
  if (tid < 64) {
    float sum = 0.f;
#pragma unroll
    for (int k = 0; k < 8; ++k) sum += zred[tid * 9 + k];
    izl[tid] = 1.0f / sum;
  }
  __syncthreads();

  // ---- p4: pack e*invZ -> eA (A-frag: m=j, k=s), then GEMM2 ----
  {
    const int s = mh * 32 + (lane & 31);
    const float iz = izl[s];
    const int q0 = w * 4 + (s >> 4);
    const int lof = 32 * ((s >> 3) & 1);
    const int idx = s & 7;
#pragma unroll
    for (int reg = 0; reg < 16; ++reg) {
      int jl = (reg & 3) + 8 * (reg >> 2) + 4 * (lane >> 5);  // j & 31
      eA[(q0 * 64 + jl + lof) * 8 + idx] = f2b(e0[reg] * iz);
    }
  }
  __syncthreads();
  // GEMM2 O[j][h]: wave (jb = w, hh = mh)
  f32x16 o0 = {};
#pragma unroll
  for (int ks = 0; ks < 4; ++ks) {
    bf16x8 a = *(const bf16x8*)&eA[((w * 4 + ks) * 64 + lane) * 8];
    bf16x8 b0 = *(const bf16x8*)&vB[((mh * 4 + ks) * 64 + lane) * 8];
    o0 = __builtin_amdgcn_mfma_f32_32x32x16_bf16(a, b0, o0, 0, 0, 0);
  }
  // atomic s-chunk reduction into O[b][j][h] (device-scope fp32 add).
  float* op = O + (size_t)bb * (NN * HH);
  const int h0 = mh * 32 + (lane & 31);
#pragma unroll
  for (int reg = 0; reg < 16; ++reg) {
    int j = w * 32 + (reg & 3) + 8 * (reg >> 2) + 4 * (lane >> 5);
    atomicAdd(&op[j * HH + h0], o0[reg]);
  }
}

// ---------------------------------------------------------------------------
// Kernel C (ynode+coef+final fused): 64 blocks x 256 threads.
//  head: ynode[b][j] = sum_h tanh(O[b][j][h])*pw[h] + pb  (thread=(j,half),
//        32 KB L2 read per block, pair-combine via shfl_xor)
//  then: recompute coef[b] in LDS (double-acc DCT, redundant across blocks —
//        trivial), then Clenshaw per element.
// ---------------------------------------------------------------------------
__global__ __launch_bounds__(256) void final_kernel(
    const float* __restrict__ x, const float* __restrict__ O,
    const float* __restrict__ pw, const float* __restrict__ pb,
    const float* __restrict__ Cmat, float* __restrict__ y) {
  const int idx = blockIdx.x * 256 + threadIdx.x;  // [0, B*T)
  const int b = idx >> 12;
  __shared__ float yl[NN];
  __shared__ float c[NN];
  // ---- ynode phase ----
  {
    const int j = threadIdx.x >> 1;
    const int half = threadIdx.x & 1;
    const float4* Ov =
        (const float4*)(O + ((size_t)(b * NN + j) * HH + half * 32));
    const float4* pwv = (const float4*)(pw + half * 32);
    float s = 0.f;
#pragma unroll
    for (int q = 0; q < 8; ++q) {
      float4 ov = Ov[q];
      float4 pv = pwv[q];
      s += fast_tanh(ov.x) * pv.x + fast_tanh(ov.y) * pv.y +
           fast_tanh(ov.z) * pv.z + fast_tanh(ov.w) * pv.w;
    }
    s += __shfl_xor(s, 1, 64);
    if (half == 0) yl[j] = s + pb[0];
  }
  __syncthreads();
  if (threadIdx.x < NN) {
    int m = threadIdx.x;
    double acc = 0.0;
#pragma unroll 8
    for (int j = 0; j < NN; ++j)
      acc += (double)yl[j] * (double)Cmat[m * NN + j];
    c[m] = (float)(acc * ((m == 0 ? 1.0 : 2.0) / NN));
  }
  __syncthreads();
  float xf = x[idx] * (1.0f / XR);
  xf = fminf(1.0f, fmaxf(-1.0f, xf));
  double xh = (double)xf;
  double b1 = 0.0, b2 = 0.0;
  for (int m = NN - 1; m >= 1; --m) {
    double t = fma(2.0 * xh, b1, (double)c[m] - b2);
    b2 = b1;
    b1 = t;
  }
  y[idx] = (float)fma(xh, b1, (double)c[0] - b2);
}

extern "C" void kernel_launch(void* const* d_in, const int* in_sizes, int n_in,
                              void* d_out, int out_size, void* d_ws,
                              size_t ws_size, hipStream_t stream) {
  const float* x = (const float*)d_in[0];
  const float* emb = (const float*)d_in[1];
  const float* kw = (const float*)d_in[2];
  const float* kb = (const float*)d_in[3];
  const float* qw = (const float*)d_in[4];
  const float* qb = (const float*)d_in[5];
  const float* vw = (const float*)d_in[6];
  const float* pw = (const float*)d_in[7];
  const float* pb = (const float*)d_in[8];

  float* ws = (float*)d_ws;
  float* O = ws;                                          // 32768 floats
  float* Cmat = ws + 32768;                               // 16384
  unsigned short* qnA = (unsigned short*)(Cmat + 16384);  // 4096 float-slots
  unsigned int* Wfrag = (unsigned int*)(Cmat + 16384 + 4096);  // 32768 slots
  float* Sm_part = (float*)(Wfrag + 32768);               // 16384
  float* y = (float*)d_out;

  prep_sm_kernel<<<256, 256, 0, stream>>>(kw, vw, qw, qb, x, Wfrag, Cmat, qnA,
                                          Sm_part, O);
  kvattn_kernel<<<BB * SS / 64, 512, 0, stream>>>(emb, kb, Wfrag, qnA, Cmat,
                                                  Sm_part, O);
  final_kernel<<<BB * TT / 256, 256, 0, stream>>>(x, O, pw, pb, Cmat, y);
}